// Round 1
// baseline (397.552 us; speedup 1.0000x reference)
//
#include <hip/hip_runtime.h>

// LSS voxel pooling: N_POINTS=692736, C=64, B=4, NX=256, NY=256, NZ=1 (gz==0)
// final[b, c, 0, ix, iy] = sum over points at (ix,iy,b) of x[:, c]
// out flat: ((b*64 + c)*256 + ix)*256 + iy   (fp32, 64 MB)
//
// Strategy v2: single-pass fixed-capacity bucketing.
//   Mean points/voxel = 692736/262144 = 2.64 (Poisson).  P(count>16) ~ 2e-8
//   per voxel, so CAP=16 buckets (64 B = one cache line each) hold everything;
//   a device overflow list keeps the kernel correct for arbitrary inputs
//   (consumed inside gather, branch never taken in practice).
// Replaces the old 6-kernel count/scan/scan/finalize/fill/gather pipeline
// (two atomic passes + 3 scan launches) with memset + fill + gather.

#define NPTS   692736          // = 2706 * 256 exactly
#define CFEAT  64
#define NXV    256
#define NYV    256
#define NBAT   4
#define NVOX   (NBAT * NXV * NYV)   // 262144
#define CAP    16                   // bucket slots per voxel (64 B line)

typedef float f32x4 __attribute__((ext_vector_type(4)));

// ws layout (bytes):
//   [0,      1 MB)   count   (memset to 0 each call)
//   [1 MB,   +4 B)   ovf_cnt (memset to 0, same memset)
//   [1 MB+64,8 MB)   ovf pairs (v, i) — worst case NPTS entries = 5.5 MB, fits
//   [8 MB,  ~25 MB)  bucket[NVOX * CAP]

__device__ __forceinline__ int voxel_of(const int* __restrict__ geom, int i) {
    const int4 g = *(const int4*)(geom + (size_t)i * 4);   // gx, gy, gz(=0), gb
    return (g.w * NXV + g.x) * NYV + g.y;
}

// --- 1: bin point indices into fixed-capacity per-voxel buckets -------------
__global__ __launch_bounds__(256) void fill_kernel(
    const int* __restrict__ geom, int* __restrict__ count,
    int* __restrict__ bucket, int* __restrict__ ovf_cnt, int* __restrict__ ovf)
{
    int i = blockIdx.x * 256 + threadIdx.x;     // grid exact: 2706*256 == NPTS
    int v = voxel_of(geom, i);
    int pos = atomicAdd(&count[v], 1);
    if (pos < CAP) {
        bucket[(size_t)v * CAP + pos] = i;
    } else {                                    // essentially never taken
        int j = atomicAdd(ovf_cnt, 1);
        ovf[2 * j]     = v;
        ovf[2 * j + 1] = i;
    }
}

// --- 2: gather-sum, write directly in [B, C, X, Y] --------------------------
// Block = (b, ix); 512 threads = 256 iy x 2 channel-halves (32 ch each).
// Per thread: bucket entries live in ONE 64 B line -> first read pulls it,
// rest are L1 hits. x rows are read exactly once -> nontemporal.
__global__ __launch_bounds__(512) void gather_kernel(
    const float* __restrict__ x, const int* __restrict__ count,
    const int* __restrict__ bucket, const int* __restrict__ ovf_cnt,
    const int* __restrict__ ovf, float* __restrict__ out)
{
    int b  = blockIdx.x >> 8;
    int ix = blockIdx.x & 255;
    int iy = threadIdx.x & 255;
    int h  = threadIdx.x >> 8;           // channel half: c in [h*32, h*32+32)

    int v   = (b * NXV + ix) * NYV + iy;
    int cnt = count[v];
    int n   = cnt < CAP ? cnt : CAP;
    const int* __restrict__ bk = bucket + (size_t)v * CAP;

    f32x4 acc[8] = {};
    for (int k = 0; k < n; ++k) {
        int p = bk[k];
        const f32x4* row = (const f32x4*)(x + (size_t)p * CFEAT + h * 32);
        #pragma unroll
        for (int q = 0; q < 8; ++q)
            acc[q] += __builtin_nontemporal_load(row + q);
    }

    if (cnt > CAP) {                      // correctness path; never in practice
        int no = *ovf_cnt;
        for (int j = 0; j < no; ++j) {
            if (ovf[2 * j] == v) {
                int p = ovf[2 * j + 1];
                const f32x4* row = (const f32x4*)(x + (size_t)p * CFEAT + h * 32);
                #pragma unroll
                for (int q = 0; q < 8; ++q)
                    acc[q] += row[q];
            }
        }
    }

    // Writes: for each channel, 256 lanes hit consecutive iy -> 256 B bursts
    // per wave-store, full 64 B lines, no RMW. Never re-read -> nontemporal.
    size_t obase = (((size_t)b * CFEAT + h * 32) * NXV + ix) * NYV + iy;
    #pragma unroll
    for (int q = 0; q < 8; ++q) {
        #pragma unroll
        for (int j = 0; j < 4; ++j)
            __builtin_nontemporal_store(acc[q][j],
                out + obase + (size_t)(q * 4 + j) * (NXV * NYV));
    }
}

extern "C" void kernel_launch(void* const* d_in, const int* in_sizes, int n_in,
                              void* d_out, int out_size, void* d_ws, size_t ws_size,
                              hipStream_t stream) {
    const float* x  = (const float*)d_in[0];   // fp32 [NPTS,64]
    const int* geom = (const int*)d_in[1];     // [NPTS,4]
    float* out      = (float*)d_out;           // fp32 [4,64,256,256]

    char* w = (char*)d_ws;
    int* count   = (int*)(w);
    int* ovf_cnt = (int*)(w + (1u << 20));
    int* ovf     = (int*)(w + (1u << 20) + 64);
    int* bucket  = (int*)(w + (8u << 20));

    // zero count + ovf_cnt in one memset
    hipMemsetAsync(w, 0, (1u << 20) + 64, stream);

    fill_kernel  <<<NPTS / 256, 256, 0, stream>>>(geom, count, bucket, ovf_cnt, ovf);
    gather_kernel<<<NBAT * NXV, 512, 0, stream>>>(x, count, bucket, ovf_cnt, ovf, out);
}